// Round 7
// baseline (141.600 us; speedup 1.0000x reference)
//
#include <hip/hip_runtime.h>
#include <hip/hip_bf16.h>

#define KDIM 256
#define NTOT 131072
#define PN   65536        // 256*256
#define NGB  512          // gemm blocks (256 row-ranges x 2 j-halves)
#define RPB  512          // rows per gemm block
#define NTL  16           // 32-row compute tiles per block
#define CH   (32*KDIM)    // floats per tile per matrix
#define PSZ  32768        // partial elems per gemm block (256*128)
#define BUFB 24576        // LDS bytes per buffer (A 16K + B 8K)

typedef float f32x4 __attribute__((ext_vector_type(4)));
typedef __bf16 bf16x8 __attribute__((ext_vector_type(8)));

__device__ __forceinline__ unsigned short f2bf(float x){
  unsigned u = __float_as_uint(x);
  u += 0x7fffu + ((u >> 16) & 1u);   // round-to-nearest-even
  return (unsigned short)(u >> 16);
}
__device__ __forceinline__ unsigned pk2(float lo, float hi){
  return (unsigned)f2bf(lo) | ((unsigned)f2bf(hi) << 16);
}
__device__ __forceinline__ float bf2f(unsigned short u){
  return __uint_as_float((unsigned)u << 16);
}
// XOR swizzle on byte-bits 4..6 of a 64B-row layout. Applied to the FULL
// linear address everywhere (write and read) — XOR, never post-XOR adds.
__device__ __forceinline__ int swz(int i){ return (((i >> 1) ^ (i >> 4)) & 7) << 4; }

struct Stage { f32x4 r0, r1; };   // two rows, one 4-col quad, one matrix (8 VGPRs)

__device__ __forceinline__ void stage_load(Stage& s, const float* src, long off){
  s.r0 = *(const f32x4*)(src + off);
  s.r1 = *(const f32x4*)(src + off + KDIM);
}

// pW = 2 packed u16 offsets x2; x XORed in (slot-2 A trick: (lin|32)^swz == (lin^swz)^32)
__device__ __forceinline__ void stage_store(const Stage& s, char* T, const unsigned* pW, int x){
#pragma unroll
  for (int m = 0; m < 4; ++m){
    const int off = (int)((pW[m >> 1] >> ((m & 1) * 16)) & 0xffffu) ^ x;
    *(unsigned*)(T + off) = pk2(s.r0[m], s.r1[m]);
  }
}

__device__ __forceinline__ void compute_t(const char* T, const unsigned* pFa,
                                          const unsigned* pFb, f32x4 (&acc)[4][4])
{
  bf16x8 af[4];
#pragma unroll
  for (int m = 0; m < 4; ++m)
    af[m] = *(const bf16x8*)(T + ((pFa[m >> 1] >> ((m & 1) * 16)) & 0xffffu));
#pragma unroll
  for (int n = 0; n < 4; ++n){
    bf16x8 bf = *(const bf16x8*)(T + ((pFb[n >> 1] >> ((n & 1) * 16)) & 0xffffu));
#pragma unroll
    for (int m = 0; m < 4; ++m)
      acc[m][n] = __builtin_amdgcn_mfma_f32_16x16x32_bf16(af[m], bf, acc[m][n], 0, 0, 0);
  }
}

__device__ __forceinline__ void lds_fence_barrier(){
  __builtin_amdgcn_sched_barrier(0);
  asm volatile("s_waitcnt lgkmcnt(0)");
  __builtin_amdgcn_sched_barrier(0);
  __builtin_amdgcn_s_barrier();              // raw barrier: no vmcnt drain
  __builtin_amdgcn_sched_barrier(0);
}

// K1: partial_b[256 i][128 j] (bf16) over rows [r*512, r*512+512), j-half h.
// bid = h*256 + r  (h=1 blocks run after h=0 -> v1 re-read is L3-served).
__global__ __launch_bounds__(512, 4) void k_gemm(const float* __restrict__ v1,
                                                 const float* __restrict__ v2,
                                                 unsigned short* __restrict__ part)
{
  __shared__ char sm[2 * BUFB];   // buf0/buf1: A[256i][64B] @0, B[128j][64B] @16K
  const int t    = threadIdx.x;
  const int b    = blockIdx.x;
  const int r    = b & 255, h = b >> 8;
  const int lane = t & 63, wid = t >> 6;
  const int di   = lane & 15, g = lane >> 4;
  const int i0   = (wid >> 1) * 64;          // 4 wave-rows cover i 0..255
  const int j0l  = (wid & 1) * 64;           // 2 wave-cols cover local j 0..127

  // staging: A = 32 rows x 256 i per tile -> 1024 tasks = 2/thread (rpA, rpA+8)
  //          B = 32 rows x 128 j          ->  512 tasks = 1/thread
  const int rpA = t >> 6, qA = t & 63;       // rpA 0..7
  const int rpB = t >> 5, qB = t & 31;       // rpB 0..15
  const long rowBase = (long)r * RPB;
  const float* pA  = v1 + (rowBase + 2 * rpA) * KDIM + 4 * qA;
  const float* pA2 = pA + 16 * KDIM;                       // rpA + 8
  const float* pB  = v2 + (rowBase + 2 * rpB) * KDIM + h * 128 + 4 * qB;

  unsigned pWa[2], pWb[2], pFa[2], pFb[2];
#pragma unroll
  for (int m = 0; m < 4; m += 2){
    const int i1 = 4*qA + m, i2 = i1 + 1;
    pWa[m>>1] = (unsigned)((((i1 << 6) + (rpA << 2)) ^ swz(i1)) & 0xffff)
              | ((unsigned)((((i2 << 6) + (rpA << 2)) ^ swz(i2)) & 0xffff) << 16);
    const int j1 = 4*qB + m, j2 = j1 + 1;
    pWb[m>>1] = (unsigned)((16384 + (((j1 << 6) + (rpB << 2)) ^ swz(j1))) & 0xffff)
              | ((unsigned)((16384 + (((j2 << 6) + (rpB << 2)) ^ swz(j2))) & 0xffff) << 16);
    const int ia = i0 + 16*m + di, ib = i0 + 16*(m+1) + di;
    pFa[m>>1] = (unsigned)((((ia << 6) + (g << 4)) ^ swz(ia)) & 0xffff)
              | ((unsigned)((((ib << 6) + (g << 4)) ^ swz(ib)) & 0xffff) << 16);
    const int ja = j0l + 16*m + di, jb = j0l + 16*(m+1) + di;
    pFb[m>>1] = (unsigned)((16384 + (((ja << 6) + (g << 4)) ^ swz(ja))) & 0xffff)
              | ((unsigned)((16384 + (((jb << 6) + (g << 4)) ^ swz(jb))) & 0xffff) << 16);
  }

  f32x4 acc[4][4];
#pragma unroll
  for (int m = 0; m < 4; ++m)
#pragma unroll
    for (int n = 0; n < 4; ++n){ f32x4 z = {0.f,0.f,0.f,0.f}; acc[m][n] = z; }

  // --- prologue: fill tile 0, then leave tile 1's 6 loads in flight ---
  Stage A0, A1, B0;
  stage_load(A0, pA,  0);
  stage_load(A1, pA2, 0);
  stage_load(B0, pB,  0);
  stage_store(A0, sm, pWa, 0);
  stage_store(A1, sm, pWa, 32);
  stage_store(B0, sm, pWb, 0);
  __builtin_amdgcn_sched_barrier(0);
  stage_load(A0, pA,  CH);
  stage_load(A1, pA2, CH);
  stage_load(B0, pB,  CH);
  lds_fence_barrier();

  // --- main loop: iter it stores tile it+1 (loaded a full iter ago, counted
  //     vmcnt(4)), issues tile it+2's loads, computes tile it. 1 barrier/iter.
#pragma unroll 2
  for (int it = 0; it < NTL - 2; ++it){
    char* Tc = sm + (it & 1) * BUFB;
    char* Tn = sm + ((it + 1) & 1) * BUFB;
    stage_store(A0, Tn, pWa, 0);
    __builtin_amdgcn_sched_barrier(0);
    stage_load(A0, pA,  (long)(it + 2) * CH);
    __builtin_amdgcn_sched_barrier(0);
    stage_store(A1, Tn, pWa, 32);
    __builtin_amdgcn_sched_barrier(0);
    stage_load(A1, pA2, (long)(it + 2) * CH);
    __builtin_amdgcn_sched_barrier(0);
    stage_store(B0, Tn, pWb, 0);
    __builtin_amdgcn_sched_barrier(0);
    stage_load(B0, pB,  (long)(it + 2) * CH);
    __builtin_amdgcn_sched_barrier(0);
    compute_t(Tc, pFa, pFb, acc);
    lds_fence_barrier();
  }

  // --- epilogue: store tile 15 (tail vmcnt drain ok), compute tiles 14, 15 ---
  {
    char* Tc = sm + ((NTL - 2) & 1) * BUFB;
    char* Tn = sm + ((NTL - 1) & 1) * BUFB;
    stage_store(A0, Tn, pWa, 0);
    stage_store(A1, Tn, pWa, 32);
    stage_store(B0, Tn, pWb, 0);
    __builtin_amdgcn_sched_barrier(0);
    compute_t(Tc, pFa, pFb, acc);
    lds_fence_barrier();
    compute_t(Tn, pFa, pFb, acc);
  }

  unsigned short* op = part + (size_t)b * PSZ;
#pragma unroll
  for (int m = 0; m < 4; ++m)
#pragma unroll
    for (int n = 0; n < 4; ++n){
      const int i  = i0 + 16*m + 4*g;
      const int jl = j0l + 16*n + di;
#pragma unroll
      for (int rr = 0; rr < 4; ++rr)
        op[(size_t)(i + rr) * 128 + jl] = f2bf(acc[m][n][rr]);
    }
}

// K2: P[gr][j] = sum over 256 r of part[(j>>7)*256 + r][gr][j&127];
//     also row sums rsum[gr] and (atomic) col sums csum[j].
__global__ __launch_bounds__(1024) void k_reduce(const unsigned short* __restrict__ part,
                                                 float* __restrict__ P,
                                                 float* __restrict__ rsum,
                                                 float* __restrict__ csum)
{
  __shared__ float red[1024];
  const int gr = blockIdx.x;            // P row (i)
  const int t  = threadIdx.x;
  const int j  = t & 255, q = t >> 8;   // 4-way split over r
  const int hh = j >> 7, jl = j & 127;
  float s = 0.f;
  const unsigned short* p = part + (size_t)(hh * 256 + q * 64) * PSZ + gr * 128 + jl;
  for (int k = 0; k < 64; ++k) s += bf2f(p[(size_t)k * PSZ]);
  red[t] = s; __syncthreads();
  if (t < 512) red[t] += red[t + 512];
  __syncthreads();
  float v = 0.f;
  if (t < 256){
    v = red[t] + red[t + 256];
    P[gr * KDIM + t] = v;
    atomicAdd(&csum[t], v);
  }
  __syncthreads();
  red[t] = (t < 256) ? v : 0.f;
  __syncthreads();
  for (int st = 128; st > 0; st >>= 1){
    if (t < st) red[t] += red[t + st];
    __syncthreads();
  }
  if (t == 0) rsum[gr] = red[0];
}

// K3: S = sum r ; lm[i] = log((r_i + c_i)/(2S)) ; scal[0] = 1/(2S) ; zero out[0]
__global__ __launch_bounds__(256) void k_marg(const float* __restrict__ rsum,
                                              const float* __restrict__ csum,
                                              float* __restrict__ lm,
                                              float* __restrict__ scal,
                                              float* __restrict__ out)
{
  __shared__ float red[256];
  const int i = threadIdx.x;
  float ri = rsum[i];
  red[i] = ri; __syncthreads();
  for (int st = 128; st > 0; st >>= 1){
    if (i < st) red[i] += red[i + st];
    __syncthreads();
  }
  const float S = red[0];
  const float inv2S = 0.5f / S;
  float mi = (ri + csum[i]) * inv2S;
  mi = fmaxf(mi, 2.220446049250313e-16f);
  lm[i] = logf(mi);
  if (i == 0){ scal[0] = inv2S; out[0] = 0.f; }
}

// K4: loss = sum_ij -q*(log q - 10*(lm_i + lm_j)),  q = (P_ij + P_ji)/(2S)
__global__ __launch_bounds__(256) void k_loss(const float* __restrict__ P,
                                              const float* __restrict__ lm,
                                              const float* __restrict__ scal,
                                              float* __restrict__ out)
{
  __shared__ float red[256];
  const float inv2S = scal[0];
  float acc = 0.f;
  const int base = blockIdx.x * 512;
  for (int e = base + threadIdx.x; e < base + 512; e += 256){
    const int i = e >> 8, j = e & 255;
    float q = (P[i * KDIM + j] + P[j * KDIM + i]) * inv2S;
    q = fmaxf(q, 2.220446049250313e-16f);
    acc += -q * (logf(q) - 10.0f * (lm[i] + lm[j]));
  }
  red[threadIdx.x] = acc; __syncthreads();
  for (int st = 128; st > 0; st >>= 1){
    if (threadIdx.x < st) red[threadIdx.x] += red[threadIdx.x + st];
    __syncthreads();
  }
  if (threadIdx.x == 0) atomicAdd(out, red[0]);
}

extern "C" void kernel_launch(void* const* d_in, const int* in_sizes, int n_in,
                              void* d_out, int out_size, void* d_ws, size_t ws_size,
                              hipStream_t stream) {
  const float* v1 = (const float*)d_in[0];
  const float* v2 = (const float*)d_in[1];
  float* out = (float*)d_out;
  char*  wsc = (char*)d_ws;

  unsigned short* part = (unsigned short*)wsc;                 // NGB*PSZ bf16 = 32 MB
  float* P    = (float*)(wsc + (size_t)NGB * PSZ * 2);         // 256 KB
  float* rsum = P + PN;
  float* csum = rsum + 256;
  float* lm   = csum + 256;
  float* scal = lm + 256;

  hipMemsetAsync(csum, 0, 256 * sizeof(float), stream);
  k_gemm  <<<NGB, 512, 0, stream>>>(v1, v2, part);
  k_reduce<<<256, 1024, 0, stream>>>(part, P, rsum, csum);
  k_marg  <<<1, 256, 0, stream>>>(rsum, csum, lm, scal, out);
  k_loss  <<<128, 256, 0, stream>>>(P, lm, scal, out);
}

// Round 8
// 71.600 us; speedup vs baseline: 1.9776x; 1.9776x over previous
//
#include <hip/hip_runtime.h>
#include <hip/hip_bf16.h>

#define KDIM 256
#define NTOT 131072
#define PN   65536        // 256*256
#define NB   256          // split-K blocks
#define RPB  512          // rows per block = NTOT/NB
#define CHROWS 16         // rows per staging chunk
#define CH   (CHROWS*KDIM) // floats per chunk per matrix
#define NTL  16           // compute tiles per block (32 rows each)
#define EPSF 2.220446049250313e-16f

typedef float f32x4 __attribute__((ext_vector_type(4)));
typedef __bf16 bf16x8 __attribute__((ext_vector_type(8)));

__device__ __forceinline__ unsigned short f2bf(float x){
  unsigned u = __float_as_uint(x);
  u += 0x7fffu + ((u >> 16) & 1u);   // round-to-nearest-even
  return (unsigned short)(u >> 16);
}
__device__ __forceinline__ unsigned pk2(float lo, float hi){
  return (unsigned)f2bf(lo) | ((unsigned)f2bf(hi) << 16);
}
__device__ __forceinline__ float bf2f(unsigned short u){
  return __uint_as_float((unsigned)u << 16);
}
// XOR swizzle on byte-bits 4..6 of a 64B-row layout.
// Applied to the FULL linear address everywhere (write and read).
__device__ __forceinline__ int swz(int i){ return (((i >> 1) ^ (i >> 4)) & 7) << 4; }

struct Stage { f32x4 r0, r1; };   // two rows, same 4-col quad, ONE matrix (8 VGPRs)

__device__ __forceinline__ void stage_load(Stage& s, const float* src, long off){
  s.r0 = *(const f32x4*)(src + off);
  s.r1 = *(const f32x4*)(src + off + KDIM);
}

__device__ __forceinline__ void stage_store(const Stage& s, char* tile, const int* offW){
#pragma unroll
  for (int m = 0; m < 4; ++m)
    *(unsigned*)(tile + offW[m]) = pk2(s.r0[m], s.r1[m]);
}

__device__ __forceinline__ void compute_t(const char* As, const char* Bs,
                                          const int* offA, const int* offB,
                                          f32x4 (&acc)[4][4])
{
  bf16x8 af[4], bfr[4];
#pragma unroll
  for (int m = 0; m < 4; ++m) af[m]  = *(const bf16x8*)(As + offA[m]);
#pragma unroll
  for (int n = 0; n < 4; ++n) bfr[n] = *(const bf16x8*)(Bs + offB[n]);
#pragma unroll
  for (int m = 0; m < 4; ++m)
#pragma unroll
    for (int n = 0; n < 4; ++n)
      acc[m][n] = __builtin_amdgcn_mfma_f32_16x16x32_bf16(af[m], bfr[n], acc[m][n], 0, 0, 0);
}

__device__ __forceinline__ void lds_fence_barrier(){
  __builtin_amdgcn_sched_barrier(0);
  asm volatile("s_waitcnt lgkmcnt(0)");
  __builtin_amdgcn_sched_barrier(0);
  __builtin_amdgcn_s_barrier();              // raw barrier: no vmcnt drain
  __builtin_amdgcn_sched_barrier(0);
}

// K1: partial_b[256][256] (bf16) = sum over this block's 512-row N-chunk of v1[n][i]*v2[n][j]
// Block 0 also zeroes csum (consumed only by k_reduce, which launches after).
__global__ __launch_bounds__(1024) void k_gemm(const float* __restrict__ v1,
                                               const float* __restrict__ v2,
                                               unsigned short* __restrict__ part,
                                               float* __restrict__ csum)
{
  __shared__ char sm[65536];   // tile T0: A@0 B@16K ; tile T1: A@32K B@48K (32 n-rows, 64B i-rows)
  const int t    = threadIdx.x;
  const int b    = blockIdx.x;
  if (b == 0 && t < 256) csum[t] = 0.f;
  const int lane = t & 63, wid = t >> 6;
  const int di   = lane & 15, g = lane >> 4;
  const int wr   = wid >> 2, wc = wid & 3;
  const int i0   = wr * 64, j0 = wc * 64;   // 4x4 waves, 64x64 output tile each

  // staging assignment: 512 threads per matrix; thread = (matrix, row-pair p, col-quad q)
  const int mtx = t >> 9;            // 0: v1/A, 1: v2/B
  const int p   = (t >> 6) & 7;      // row-pair within 16-row chunk
  const int q   = t & 63;            // 4-col quad
  const float* src = (mtx ? v2 : v1) + ((long)b * RPB + 2 * p) * KDIM + 4 * q;
  const int sbase = mtx * 16384;     // A sub-tile at +0, B at +16K within a tile buffer

  int offW0[4], offW1[4], offA[4], offB[4];
#pragma unroll
  for (int m = 0; m < 4; ++m){
    const int i   = 4*q + m;
    const int lin = (i << 6) + (p << 2);
    offW0[m] = sbase + ( lin        ^ swz(i));   // even chunk -> words 0..7
    offW1[m] = sbase + ((lin + 32)  ^ swz(i));   // odd chunk  -> words 8..15
  }
#pragma unroll
  for (int m = 0; m < 4; ++m){ int i = i0 + 16*m + di; offA[m] = ((i << 6) + (g << 4)) ^ swz(i); }
#pragma unroll
  for (int n = 0; n < 4; ++n){ int j = j0 + 16*n + di; offB[n] = ((j << 6) + (g << 4)) ^ swz(j); }

  f32x4 acc[4][4];
#pragma unroll
  for (int m = 0; m < 4; ++m)
#pragma unroll
    for (int n = 0; n < 4; ++n){ f32x4 z = {0.f,0.f,0.f,0.f}; acc[m][n] = z; }

  // --- prologue: fill tile 0 (chunks 0,1); leave chunks 2,3 in flight ---
  Stage S0, S1;
  stage_load(S0, src, 0L * CH);
  stage_load(S1, src, 1L * CH);
  stage_store(S0, sm, offW0);                // auto vmcnt(2): S1's loads stay in flight
  __builtin_amdgcn_sched_barrier(0);
  stage_load(S0, src, 2L * CH);
  __builtin_amdgcn_sched_barrier(0);
  stage_store(S1, sm, offW1);
  __builtin_amdgcn_sched_barrier(0);
  stage_load(S1, src, 3L * CH);
  lds_fence_barrier();

  // --- main loop: iter it computes tile it from T[it&1], fills tile it+1 into T[(it+1)&1],
  //     and issues chunks 2it+4, 2it+5 (stored next iter -> full-iteration latency window) ---
#pragma unroll 2
  for (int it = 0; it < NTL - 2; ++it){
    char* Tc = sm + (it & 1) * 32768;
    char* Tn = sm + ((it + 1) & 1) * 32768;
    stage_store(S0, Tn, offW0);              // chunk 2it+2 (auto counted vmcnt(2))
    __builtin_amdgcn_sched_barrier(0);
    stage_load(S0, src, (long)(2*it + 4) * CH);
    __builtin_amdgcn_sched_barrier(0);
    stage_store(S1, Tn, offW1);              // chunk 2it+3
    __builtin_amdgcn_sched_barrier(0);
    stage_load(S1, src, (long)(2*it + 5) * CH);
    __builtin_amdgcn_sched_barrier(0);
    compute_t(Tc, Tc + 16384, offA, offB, acc);
    lds_fence_barrier();
  }

  // --- epilogue: store last chunks 30,31 (no new issues), compute tiles 14,15 ---
  {
    char* Tc = sm + ((NTL - 2) & 1) * 32768;   // T0
    char* Tn = sm + ((NTL - 1) & 1) * 32768;   // T1
    stage_store(S0, Tn, offW0);                // chunk 30
    stage_store(S1, Tn, offW1);                // chunk 31 (drains vmcnt, tail only)
    __builtin_amdgcn_sched_barrier(0);
    compute_t(Tc, Tc + 16384, offA, offB, acc);   // tile 14
    lds_fence_barrier();
    compute_t(Tn, Tn + 16384, offA, offB, acc);   // tile 15
  }

  unsigned short* op = part + (size_t)b * PN;
#pragma unroll
  for (int m = 0; m < 4; ++m)
#pragma unroll
    for (int n = 0; n < 4; ++n){
      const int i = i0 + 16*m + 4*g;
      const int j = j0 + 16*n + di;
#pragma unroll
      for (int r = 0; r < 4; ++r)
        op[(size_t)(i + r) * KDIM + j] = f2bf(acc[m][n][r]);
    }
}

// K2: P = sum_b part_b ; row sums rsum[gr]; (atomic) col sums csum[j].
// Vectorized: ushort4 loads (8B/lane), 16-way r-split, LDS combine.
// Block 0 zeroes out[0] (consumed only by k_loss, launched after).
__global__ __launch_bounds__(1024) void k_reduce(const unsigned short* __restrict__ part,
                                                 float* __restrict__ P,
                                                 float* __restrict__ rsum,
                                                 float* __restrict__ csum,
                                                 float* __restrict__ out)
{
  __shared__ float red[16][256];
  const int gr = blockIdx.x;            // P row (i)
  const int t  = threadIdx.x;
  const int q  = t >> 6;                // 0..15 r-split
  const int jq = t & 63;                // j-quad
  f32x4 a = {0.f, 0.f, 0.f, 0.f};
  const unsigned short* p = part + (size_t)(q * 16) * PN + gr * KDIM + 4 * jq;
  for (int k = 0; k < 16; ++k){
    const ushort4 u = *(const ushort4*)(p + (size_t)k * PN);
    a[0] += bf2f(u.x); a[1] += bf2f(u.y); a[2] += bf2f(u.z); a[3] += bf2f(u.w);
  }
  *(f32x4*)&red[q][4 * jq] = a;
  __syncthreads();
  float v = 0.f;
  if (t < 256){
#pragma unroll
    for (int qq = 0; qq < 16; ++qq) v += red[qq][t];
    P[gr * KDIM + t] = v;
    atomicAdd(&csum[t], v);
  }
  __syncthreads();
  if (t < 256) red[0][t] = v;
  __syncthreads();
  for (int st = 128; st > 0; st >>= 1){
    if (t < st) red[0][t] += red[0][t + st];
    __syncthreads();
  }
  if (t == 0){
    rsum[gr] = red[0][0];
    if (gr == 0) out[0] = 0.f;
  }
}

// K3 (fused marg+loss): each block recomputes S and lm[256] locally (cheap),
// then its slice of loss = sum_ij -q*(log q - 10*(lm_i + lm_j)), q=(P_ij+P_ji)/(2S).
// 128 blocks x 256 threads, one atomicAdd per block into out[0].
__global__ __launch_bounds__(256) void k_loss(const float* __restrict__ P,
                                              const float* __restrict__ rsum,
                                              const float* __restrict__ csum,
                                              float* __restrict__ out)
{
  __shared__ float lm[256];
  __shared__ float red[256];
  const int t = threadIdx.x;
  const float ri = rsum[t];
  red[t] = ri; __syncthreads();
  for (int st = 128; st > 0; st >>= 1){
    if (t < st) red[t] += red[t + st];
    __syncthreads();
  }
  const float S = red[0];
  const float inv2S = 0.5f / S;
  lm[t] = logf(fmaxf((ri + csum[t]) * inv2S, EPSF));
  __syncthreads();

  float acc = 0.f;
  const int base = blockIdx.x * 512;
#pragma unroll
  for (int e = base + t; e < base + 512; e += 256){
    const int i = e >> 8, j = e & 255;
    float qv = (P[i * KDIM + j] + P[j * KDIM + i]) * inv2S;
    qv = fmaxf(qv, EPSF);
    acc += -qv * (logf(qv) - 10.0f * (lm[i] + lm[j]));
  }
  red[t] = acc; __syncthreads();
  for (int st = 128; st > 0; st >>= 1){
    if (t < st) red[t] += red[t + st];
    __syncthreads();
  }
  if (t == 0) atomicAdd(out, red[0]);
}

extern "C" void kernel_launch(void* const* d_in, const int* in_sizes, int n_in,
                              void* d_out, int out_size, void* d_ws, size_t ws_size,
                              hipStream_t stream) {
  const float* v1 = (const float*)d_in[0];
  const float* v2 = (const float*)d_in[1];
  float* out = (float*)d_out;
  char*  wsc = (char*)d_ws;

  unsigned short* part = (unsigned short*)wsc;                 // NB*PN bf16 = 32 MB
  float* P    = (float*)(wsc + (size_t)NB * PN * 2);           // 256 KB
  float* rsum = P + PN;
  float* csum = rsum + 256;

  k_gemm  <<<NB, 1024, 0, stream>>>(v1, v2, part, csum);
  k_reduce<<<256, 1024, 0, stream>>>(part, P, rsum, csum, out);
  k_loss  <<<128, 256, 0, stream>>>(P, rsum, csum, out);
}